// Round 3
// baseline (282.659 us; speedup 1.0000x reference)
//
#include <hip/hip_runtime.h>

// EdgeLoss: mean(|sobel_x(sr)-sobel_x(hr)| + |sobel_y(sr)-sobel_y(hr)|)
// = mean(|sobel_x(d)| + |sobel_y(d)|), d = sr - hr (conv linearity; abs
// erases the kernel-flip sign). Separable: s=[1,2,1]*d, t=[1,0,-1]*d
// (horiz); gx=[1,2,1]^T*t, gy=[1,0,-1]^T*s (vert).
//
// R7 = R6's counted-vmcnt ring pipeline at R5's occupancy.
// Cross-round evidence: R4 (reg, 11.5 waves/CU) 113us; R5 (DMA one-shot,
// 2 blk/CU) 105us; R6 (DMA ring, 1 blk/CU) 116us. VALUBusy ~12% and HBM
// ~19% everywhere -> latency-bound; TLP beats pipeline depth. Fix: CH=4
// shrinks the ring to 10 row-slots = 80 KiB -> ring pipeline AND 2
// blocks/CU. Persistent strips (512 blocks = exactly 2/CU) kill the
// dispatch/retire gaps R5's 15% occupancy exposed.
// Also: halo ds_read_b32 at 16B stride was an 8-way bank conflict
// (3.93M conflict-cycles/dispatch) -> use __shfl of in-register d;
// only lanes 0/63 read the cross-wave LDS column (exec-masked).
//
// Ring math (CH=4, RING=10): chunk k reads slots (4k..4k+5)%10. Stage at
// iter k writes rows l=4k+10..4k+13 into slots (4k..4k+3)%10 -- last read
// by chunk k itself, retired by the lgkmcnt(0)+barrier just before.
// vmcnt(8) after each stage => chunk k+1's 6-row window resident; never
// drain to 0 in the main loop (T3/T4).

#define IMG_H 1024
#define IMG_W 1024
#define IMG_B 32
#define CH 4                       // output rows per chunk
#define NCHUNK 16                  // chunks per strip -> 64 rows/strip
#define STRIPS 16                  // IMG_H / (CH*NCHUNK); grid (16,32)=512
#define RING 10                    // 6-row window + 4-row prefetch

#define GLOBAL_PTR(p) ((const __attribute__((address_space(1))) void*)(p))
#define LDS_PTR(p)    ((__attribute__((address_space(3))) void*)(p))

__device__ __forceinline__ void row_st(const float* __restrict__ a,
                                       const float* __restrict__ b,
                                       int x0, int lane, float m,
                                       float4& s, float4& t) {
    const float4 av = *reinterpret_cast<const float4*>(a + x0);   // ds_read_b128
    const float4 bv = *reinterpret_cast<const float4*>(b + x0);
    float4 d;
    d.x = (av.x - bv.x) * m;
    d.y = (av.y - bv.y) * m;
    d.z = (av.z - bv.z) * m;
    d.w = (av.w - bv.w) * m;
    // halo via register shuffle (conflict-free); LDS only for the 2
    // wave-boundary lanes (exec-masked ds_read_b32, cross-wave column).
    float dl = __shfl_up(d.w, 1);
    float dr = __shfl_down(d.x, 1);
    if (lane == 0)
        dl = (x0 > 0)         ? (a[x0 - 1] - b[x0 - 1]) * m : 0.f;
    if (lane == 63)
        dr = (x0 + 4 < IMG_W) ? (a[x0 + 4] - b[x0 + 4]) * m : 0.f;
    s.x = dl  + 2.f * d.x + d.y;
    s.y = d.x + 2.f * d.y + d.z;
    s.z = d.y + 2.f * d.z + d.w;
    s.w = d.z + 2.f * d.w + dr;
    t.x = dl  - d.y;
    t.y = d.x - d.z;
    t.z = d.y - d.w;
    t.w = d.z - dr;
}

__global__ __launch_bounds__(256) void edge_loss_kernel(
        const float* __restrict__ sr, const float* __restrict__ hr,
        float* __restrict__ out, float invN) {
    // 2 * 10 * 1024 * 4 B = 81920 B -> exactly 2 blocks/CU.
    __shared__ __align__(16) float lA[RING][IMG_W];
    __shared__ __align__(16) float lB[RING][IMG_W];

    const int strip = blockIdx.x;
    const int b     = blockIdx.y;
    const int tid   = threadIdx.x;
    const int lane  = tid & 63;
    const int wave  = tid >> 6;
    const int x0    = tid * 4;          // this thread's 4-col strip
    const int wseg  = wave * 256;       // this wave's 256-col row segment
    const size_t img = (size_t)b * IMG_H * IMG_W;
    const int r0 = strip * (CH * NCHUNK);   // first output row of strip

    // Stage local row l (global row r0-1+l, clamped; masked in compute)
    // into ring slot. 2 global_load_lds, no VGPR dst, no waits.
    auto stage = [&](int l, int slot) {
        const int yc = min(max(r0 - 1 + l, 0), IMG_H - 1);
        const size_t off = img + (size_t)yc * IMG_W + wseg + lane * 4;
        __builtin_amdgcn_global_load_lds(GLOBAL_PTR(sr + off), LDS_PTR(&lA[slot][wseg]), 16, 0, 0);
        __builtin_amdgcn_global_load_lds(GLOBAL_PTR(hr + off), LDS_PTR(&lB[slot][wseg]), 16, 0, 0);
    };

    // ---- prologue: l=0..9 (chunk0 window l=0..5 + chunk1's new l=6..9).
    // Wait for chunk0's 12 loads only: vmcnt(8).
    #pragma unroll
    for (int l = 0; l < RING; ++l) stage(l, l);
    asm volatile("s_waitcnt vmcnt(8)" ::: "memory");
    __builtin_amdgcn_s_barrier();

    float acc = 0.f;
    int kb = 0;                         // (CH*k) % RING, incremental

    for (int k = 0; k < NCHUNK; ++k) {
        // ---- compute chunk k from slots (kb .. kb+5) mod RING ----
        const int l0 = CH * k;          // local row of window top

        float4 s0, t0, s1, t1, s2, t2;
        {
            const float m0 = ((unsigned)(r0 - 1 + l0)     < IMG_H) ? 1.f : 0.f;
            const float m1 = ((unsigned)(r0 - 1 + l0 + 1) < IMG_H) ? 1.f : 0.f;
            int sl0 = kb;
            int sl1 = kb + 1; if (sl1 >= RING) sl1 -= RING;
            row_st(lA[sl0], lB[sl0], x0, lane, m0, s0, t0);
            row_st(lA[sl1], lB[sl1], x0, lane, m1, s1, t1);
        }
        #pragma unroll
        for (int i = 2; i < CH + 2; ++i) {
            int sl = kb + i; if (sl >= RING) sl -= RING;
            const float m = ((unsigned)(r0 - 1 + l0 + i) < IMG_H) ? 1.f : 0.f;
            row_st(lA[sl], lB[sl], x0, lane, m, s2, t2);

            float gx, gy;
            gx = t0.x + 2.f * t1.x + t2.x;  gy = s0.x - s2.x;  acc += fabsf(gx) + fabsf(gy);
            gx = t0.y + 2.f * t1.y + t2.y;  gy = s0.y - s2.y;  acc += fabsf(gx) + fabsf(gy);
            gx = t0.z + 2.f * t1.z + t2.z;  gy = s0.z - s2.z;  acc += fabsf(gx) + fabsf(gy);
            gx = t0.w + 2.f * t1.w + t2.w;  gy = s0.w - s2.w;  acc += fabsf(gx) + fabsf(gy);

            s0 = s1; t0 = t1; s1 = s2; t1 = t2;
        }

        if (k < NCHUNK - 1) {
            // retire barrier: all waves done reading slots (kb..kb+3).
            asm volatile("s_waitcnt lgkmcnt(0)" ::: "memory");
            __builtin_amdgcn_s_barrier();

            if (k < NCHUNK - 2) {
                // stage chunk k+2's new rows l=4k+10..4k+13 into the
                // just-retired slots (kb..kb+3) mod RING.
                #pragma unroll
                for (int j = 0; j < CH; ++j) {
                    int sl = kb + j; if (sl >= RING) sl -= RING;
                    stage(CH * k + RING + j, sl);
                }
                // counted: chunk k+1's 8 loads landed; ours stay in flight.
                asm volatile("s_waitcnt vmcnt(8)" ::: "memory");
            } else {
                // k == NCHUNK-2: no more prefetch; drain chunk 15's rows.
                asm volatile("s_waitcnt vmcnt(0)" ::: "memory");
            }
            __builtin_amdgcn_s_barrier();
        }

        kb += CH; if (kb >= RING) kb -= RING;
    }

    // ---- reduction: wave shuffle -> LDS (reuse lA) -> 1 atomic/block ----
    #pragma unroll
    for (int off = 32; off > 0; off >>= 1)
        acc += __shfl_down(acc, off, 64);

    __syncthreads();                 // all LDS reads of the ring complete
    if (lane == 0) lA[0][wave] = acc;
    __syncthreads();
    if (tid == 0) {
        const float bsum = lA[0][0] + lA[0][1] + lA[0][2] + lA[0][3];
        atomicAdd(out, bsum * invN);
    }
}

extern "C" void kernel_launch(void* const* d_in, const int* in_sizes, int n_in,
                              void* d_out, int out_size, void* d_ws, size_t ws_size,
                              hipStream_t stream) {
    const float* sr = (const float*)d_in[0];
    const float* hr = (const float*)d_in[1];
    float* out = (float*)d_out;

    hipMemsetAsync(out, 0, sizeof(float), stream);

    dim3 grid(STRIPS, IMG_B);
    const float invN = 1.0f / (float)((size_t)IMG_B * IMG_H * IMG_W);
    edge_loss_kernel<<<grid, 256, 0, stream>>>(sr, hr, out, invN);
}

// Round 4
// 280.470 us; speedup vs baseline: 1.0078x; 1.0078x over previous
//
#include <hip/hip_runtime.h>

// EdgeLoss: mean(|sobel_x(sr)-sobel_x(hr)| + |sobel_y(sr)-sobel_y(hr)|)
// = mean(|sobel_x(d)| + |sobel_y(d)|), d = sr - hr (conv linearity; abs
// erases the kernel-flip sign). Separable: s=[1,2,1]*d, t=[1,0,-1]*d
// (horiz); gx = t_{y-1}+2t_y+t_{y+1}, gy = s_{y-1}-s_{y+1} (vert).
//
// R8: R4-R7 (reg-batch / DMA one-shot / ring x2) all pinned at 105-116us
// with every pipe idle -> load-path throughput invariant at ~2.5 TB/s.
// Little's law: all four designs average only ~3-6 KB in flight per CU
// (bursty issue: load burst, then dead compute+barrier phase). Fix:
// continuous issue. Each WAVE independently owns a 256x16 tile, issues
// 4 load instrs (2 KB) EVERY row-step, no barriers, no LDS staging,
// double-buffered rows in registers (full unroll -> static indexing).
// 8192 waves, up to 8 blocks/CU resident -> ~30 KB/CU in flight at
// ~100% duty -> memory-side saturated. 3x logical row reuse served by
// L2 (adjacent strips co-resident); overfetch 18/16 = 1.125x.

#define IMG_H 1024
#define IMG_W 1024
#define IMG_B 32
#define WROWS 16                    // output rows per wave
#define NLOAD (WROWS + 2)           // rows touched per wave (halo incl.)
#define RSTRIPS (IMG_H / WROWS)     // 64 row-strips per image
#define NBLK (IMG_B * RSTRIPS)      // 2048 blocks x 256 thr (4 waves)

struct RowBuf { float4 a, b; float ha, hb; };

__global__ __launch_bounds__(256) void edge_loss_kernel(
        const float* __restrict__ sr, const float* __restrict__ hr,
        float* __restrict__ out, float invN) {
    const int tid  = threadIdx.x;
    const int lane = tid & 63;
    const int wv   = tid >> 6;            // col-strip 0..3 within the row
    const int bidx = blockIdx.x;
    const int b    = bidx >> 6;           // image index
    const int ys   = bidx & 63;           // row-strip index
    const int y0   = ys * WROWS;          // first output row
    const int x0   = wv * 256 + lane * 4; // this thread's 4-col strip
    const size_t img = (size_t)b * IMG_H * IMG_W;

    // Halo column: lane 0 fetches its left neighbor column, lane 63 its
    // right neighbor column (one masked scalar load per tensor per row).
    const bool edge = (lane == 0) | (lane == 63);
    const int  hx   = (lane == 0) ? x0 - 1 : x0 + 4;
    const float hm  = ((unsigned)hx < IMG_W) ? 1.f : 0.f;  // 0 at image edge
    const int  hxc  = min(max(hx, 0), IMG_W - 1);

    // Load local row l (global row y0-1+l, clamped; zeroed via mask in ST).
    auto LOAD = [&](int l, RowBuf& r) {
        const int rc = min(max(y0 - 1 + l, 0), IMG_H - 1);
        const size_t row = img + (size_t)rc * IMG_W;
        r.a = *reinterpret_cast<const float4*>(sr + row + x0);
        r.b = *reinterpret_cast<const float4*>(hr + row + x0);
        if (edge) { r.ha = sr[row + hxc]; r.hb = hr[row + hxc]; }
        else      { r.ha = 0.f;           r.hb = 0.f;           }
    };

    // Horizontal pass: d = (a-b)*m, s = [1,2,1]*d, t = [1,0,-1]*d.
    auto ST = [&](const RowBuf& r, float m, float4& s, float4& t) {
        float4 d;
        d.x = (r.a.x - r.b.x) * m;
        d.y = (r.a.y - r.b.y) * m;
        d.z = (r.a.z - r.b.z) * m;
        d.w = (r.a.w - r.b.w) * m;
        const float h = (r.ha - r.hb) * (m * hm);
        float dl = __shfl_up(d.w, 1);
        float dr = __shfl_down(d.x, 1);
        if (lane == 0)  dl = h;
        if (lane == 63) dr = h;
        s.x = dl  + 2.f * d.x + d.y;
        s.y = d.x + 2.f * d.y + d.z;
        s.z = d.y + 2.f * d.z + d.w;
        s.w = d.z + 2.f * d.w + dr;
        t.x = dl  - d.y;
        t.y = d.x - d.z;
        t.z = d.y - d.w;
        t.w = d.z - dr;
    };

    // ---- software pipeline: two row buffers, depth-1 prefetch ----
    RowBuf b0, b1;
    LOAD(0, b0);
    LOAD(1, b1);

    float4 s0, t0, s1, t1, s2, t2;
    const float mT = (y0 > 0) ? 1.f : 0.f;   // row y0-1 exists?
    ST(b0, mT, s0, t0);                      // l=0
    LOAD(2, b0);
    ST(b1, 1.f, s1, t1);                     // l=1 (row y0, always valid)
    LOAD(3, b1);

    float acc = 0.f;
    #pragma unroll
    for (int i = 0; i < WROWS; ++i) {        // output row y0+i (local l=i+1)
        RowBuf& cur = (i & 1) ? b1 : b0;     // holds local row l=i+2
        const float m = ((unsigned)(y0 + i + 1) < IMG_H) ? 1.f : 0.f;
        ST(cur, m, s2, t2);
        if (i + 4 < NLOAD) LOAD(i + 4, cur); // issue next row immediately

        float gx, gy;
        gx = t0.x + 2.f * t1.x + t2.x;  gy = s0.x - s2.x;  acc += fabsf(gx) + fabsf(gy);
        gx = t0.y + 2.f * t1.y + t2.y;  gy = s0.y - s2.y;  acc += fabsf(gx) + fabsf(gy);
        gx = t0.z + 2.f * t1.z + t2.z;  gy = s0.z - s2.z;  acc += fabsf(gx) + fabsf(gy);
        gx = t0.w + 2.f * t1.w + t2.w;  gy = s0.w - s2.w;  acc += fabsf(gx) + fabsf(gy);

        s0 = s1; t0 = t1; s1 = s2; t1 = t2;
    }

    // ---- reduction: wave shuffle -> 16B LDS -> 1 atomic/block ----
    #pragma unroll
    for (int off = 32; off > 0; off >>= 1)
        acc += __shfl_down(acc, off, 64);

    __shared__ float wsum[4];
    if (lane == 0) wsum[wv] = acc;
    __syncthreads();
    if (tid == 0) {
        const float bsum = wsum[0] + wsum[1] + wsum[2] + wsum[3];
        atomicAdd(out, bsum * invN);
    }
}

extern "C" void kernel_launch(void* const* d_in, const int* in_sizes, int n_in,
                              void* d_out, int out_size, void* d_ws, size_t ws_size,
                              hipStream_t stream) {
    const float* sr = (const float*)d_in[0];
    const float* hr = (const float*)d_in[1];
    float* out = (float*)d_out;

    hipMemsetAsync(out, 0, sizeof(float), stream);

    const float invN = 1.0f / (float)((size_t)IMG_B * IMG_H * IMG_W);
    edge_loss_kernel<<<dim3(NBLK), 256, 0, stream>>>(sr, hr, out, invN);
}